// Round 6
// baseline (3347.155 us; speedup 1.0000x reference)
//
#include <hip/hip_runtime.h>
#include <hip/hip_bf16.h>
#include <cstdint>
#include <cmath>
#include <vector>
#include <algorithm>
#include <numeric>

// ---------------------------------------------------------------------------
// LapSWD loss. RNG = exact JAX partitionable threefry (verified absmax 0.0).
// R6: projection GEMM moved to bf16-split MFMA (a=hi+lo; 3 MFMAs ~ fp32
// accuracy); p stored as bf16 hi/lo from extract; bias folded into B row 147
// via p col 147 == 1.0. Sortdiff: narrowed second co-rank search.
// ---------------------------------------------------------------------------

__constant__ float KW[5] = {0.0625f, 0.25f, 0.375f, 0.25f, 0.0625f};

struct RC { unsigned int rc[128]; };

typedef __attribute__((ext_vector_type(8))) short bf16x8;
typedef __attribute__((ext_vector_type(4))) float f32x4;

// ---- threefry2x32 block cipher, exact JAX/XLA schedule ----
__host__ __device__ inline void tf2x32(uint32_t k0, uint32_t k1,
                                       uint32_t x0, uint32_t x1,
                                       uint32_t& o0, uint32_t& o1) {
  uint32_t k2 = k0 ^ k1 ^ 0x1BD11BDAu;
  x0 += k0; x1 += k1;
#define TFR(r) { x0 += x1; x1 = (x1 << r) | (x1 >> (32 - r)); x1 ^= x0; }
  TFR(13) TFR(15) TFR(26) TFR(6)   x0 += k1; x1 += k2 + 1u;
  TFR(17) TFR(29) TFR(16) TFR(24)  x0 += k2; x1 += k0 + 2u;
  TFR(13) TFR(15) TFR(26) TFR(6)   x0 += k0; x1 += k1 + 3u;
  TFR(17) TFR(29) TFR(16) TFR(24)  x0 += k1; x1 += k2 + 4u;
  TFR(13) TFR(15) TFR(26) TFR(6)   x0 += k2; x1 += k0 + 5u;
#undef TFR
  o0 = x0; o1 = x1;
}

// ---- host tables (pure constants; computed once at library load) ----
struct HostTables {
  RC rcs[5];
  uint32_t kp0[5], kp1[5];
  HostTables() {
    static const int Hs[5] = {256, 128, 64, 32, 16};
    for (int l = 0; l < 5; ++l) {
      uint32_t f0, f1;
      tf2x32(0u, 42u, 0u, (uint32_t)l, f0, f1);  // fold_in(key(42), l)
      uint32_t ik0, ik1;
      tf2x32(f0, f1, 0u, 0u, ik0, ik1);          // k_idx = split[0]
      tf2x32(f0, f1, 0u, 1u, kp0[l], kp1[l]);    // k_proj = split[1]
      int Wm6 = Hs[l] - 6;
      int n = Wm6 * Wm6;
      int nd = n < 128 ? n : 128;
      std::vector<int> perm(n);
      std::iota(perm.begin(), perm.end(), 0);
      int rounds = (int)std::ceil(3.0 * std::log((double)n) / std::log(4294967295.0));
      uint32_t key0 = ik0, key1 = ik1;
      std::vector<uint32_t> bits(n);
      std::vector<int> ord(n), tmp(n);
      for (int r = 0; r < rounds; ++r) {
        uint32_t nk0, nk1, s0, s1;
        tf2x32(key0, key1, 0u, 0u, nk0, nk1);
        tf2x32(key0, key1, 0u, 1u, s0, s1);
        key0 = nk0; key1 = nk1;
        for (int tt = 0; tt < n; ++tt) {
          uint32_t o0, o1;
          tf2x32(s0, s1, 0u, (uint32_t)tt, o0, o1);
          bits[tt] = o0 ^ o1;
        }
        std::iota(ord.begin(), ord.end(), 0);
        std::stable_sort(ord.begin(), ord.end(),
                         [&](int A, int B) { return bits[A] < bits[B]; });
        for (int i2 = 0; i2 < n; ++i2) tmp[i2] = perm[ord[i2]];
        perm.swap(tmp);
      }
      for (int d = 0; d < 128; ++d) {
        int vv = (d < nd) ? perm[d] : 0;
        rcs[l].rc[d] = ((uint32_t)(vv / Wm6) << 16) | (uint32_t)(vv % Wm6);
      }
    }
  }
};
static const HostTables g_tbl;

__device__ inline float erfinv_f(float x) {
  float w = -log1pf(-x * x);
  float p;
  if (w < 5.0f) {
    w = w - 2.5f;
    p = 2.81022636e-08f;
    p = fmaf(p, w, 3.43273939e-07f);
    p = fmaf(p, w, -3.5233877e-06f);
    p = fmaf(p, w, -4.39150654e-06f);
    p = fmaf(p, w, 0.00021858087f);
    p = fmaf(p, w, -0.00125372503f);
    p = fmaf(p, w, -0.00417768164f);
    p = fmaf(p, w, 0.246640727f);
    p = fmaf(p, w, 1.50140941f);
  } else {
    w = sqrtf(w) - 3.0f;
    p = -0.000200214257f;
    p = fmaf(p, w, 0.000100950558f);
    p = fmaf(p, w, 0.00134934322f);
    p = fmaf(p, w, -0.00367342844f);
    p = fmaf(p, w, 0.00573950773f);
    p = fmaf(p, w, -0.0076224613f);
    p = fmaf(p, w, 0.00943887047f);
    p = fmaf(p, w, 1.00167406f);
    p = fmaf(p, w, 2.83297682f);
  }
  return p * x;
}

__device__ inline float bits_to_normal(uint32_t b) {
  union { uint32_t u; float f; } cv;
  cv.u = (b >> 9) | 0x3f800000u;
  float f = cv.f - 1.0f;
  const float lo = -0.99999994f;
  const float span = 1.0f - lo;
  float u = fmaxf(lo, __fadd_rn(__fmul_rn(f, span), lo));
  return 1.41421356237f * erfinv_f(u);
}

// fp32 -> bf16 RNE + back
__device__ inline ushort f2bf(float x) {
  union { float f; uint32_t u; } c; c.f = x;
  uint32_t r = c.u + 0x7FFFu + ((c.u >> 16) & 1u);
  return (ushort)(r >> 16);
}
__device__ inline float bf2f(ushort h) {
  union { uint32_t u; float f; } c; c.u = ((uint32_t)h) << 16;
  return c.f;
}

// ---- kernels ----

__global__ void init_kernel(float* m) {
  int i = threadIdx.x;
  if (i < 128) m[i] = 0.f;
}

__global__ __launch_bounds__(256) void down_kernel(
    const float* __restrict__ in, float* __restrict__ out,
    int H, int W, int total) {
  int idx = blockIdx.x * 256 + threadIdx.x;
  if (idx >= total) return;
  int Wo = W >> 1, Ho = H >> 1;
  int ox = idx % Wo;
  int t = idx / Wo;
  int oy = t % Ho;
  int bc = t / Ho;
  const float* src = in + (size_t)bc * H * W;
  float s = 0.f;
#pragma unroll
  for (int u = 0; u < 5; ++u) {
    int y = 2 * oy + u - 2;
    if (y < 0 || y >= H) continue;
    const float* r = src + (size_t)y * W;
#pragma unroll
    for (int v = 0; v < 5; ++v) {
      int x = 2 * ox + v - 2;
      if (x < 0 || x >= W) continue;
      s += KW[u] * KW[v] * r[x];
    }
  }
  out[idx] = s;
}

__global__ void randgen_kernel(float* __restrict__ rnd, uint32_t k0, uint32_t k1) {
  int t = blockIdx.x * 256 + threadIdx.x;  // grid covers 81920
  const int total = 75264;                 // 147*512
  if (t < total) {
    uint32_t o0, o1;
    tf2x32(k0, k1, 0u, (uint32_t)t, o0, o1);
    rnd[t] = bits_to_normal(o0 ^ o1);
  }
}

// extract + per-channel stats; p emitted as bf16 hi/lo; col147 = 1.0 (bias)
__global__ __launch_bounds__(256) void extract_kernel(
    const float* __restrict__ g, const float* __restrict__ gn,
    ushort* __restrict__ pH, ushort* __restrict__ pL,
    float* __restrict__ st, RC rcs,
    int H, int nd, int useLap, int total) {
  __shared__ float ls[6];
  if (threadIdx.x < 6) ls[threadIdx.x] = 0.f;
  __syncthreads();
  int idx = blockIdx.x * 256 + threadIdx.x;
  if (idx < total) {                    // total = M*160
    int col = idx % 160;
    if (col < 147) {
      int row = idx / 160;
      int d = row % nd, b = row / nd;
      int c = col / 49, uv = col % 49, u = uv / 7, v = uv % 7;
      unsigned rc = rcs.rc[d];
      int y = (int)(rc >> 16) + u;
      int x = (int)(rc & 0xffffu) + v;
      const float* gc = g + ((size_t)(b * 3 + c)) * H * H;
      float val = gc[(size_t)y * H + x];
      if (useLap) {
        int H2 = H >> 1;
        const float* gnc = gn + ((size_t)(b * 3 + c)) * H2 * H2;
        int h = y >> 1, w = x >> 1;
        int yo = y & 1, xo = x & 1;
        float rw0 = (y >= 2) ? (yo ? 0.0625f : 0.3125f) : 0.f;
        float rw2 = (y <= H - 3) ? (yo ? 0.3125f : 0.0625f) : 0.f;
        float cw0 = (x >= 2) ? (xo ? 0.0625f : 0.3125f) : 0.f;
        float cw2 = (x <= H - 3) ? (xo ? 0.3125f : 0.0625f) : 0.f;
        int r0 = max(h - 1, 0), r2 = min(h + 1, H2 - 1);
        int c0 = max(w - 1, 0), c2 = min(w + 1, H2 - 1);
        const float* R0 = gnc + (size_t)r0 * H2;
        const float* R1 = gnc + (size_t)h * H2;
        const float* R2 = gnc + (size_t)r2 * H2;
        float s0 = cw0 * R0[c0] + 0.625f * R0[w] + cw2 * R0[c2];
        float s1 = cw0 * R1[c0] + 0.625f * R1[w] + cw2 * R1[c2];
        float s2 = cw0 * R2[c0] + 0.625f * R2[w] + cw2 * R2[c2];
        val -= rw0 * s0 + 0.625f * s1 + rw2 * s2;
      }
      ushort hb = f2bf(val);
      pH[idx] = hb;
      pL[idx] = f2bf(val - bf2f(hb));
      atomicAdd(&ls[c], val);
      atomicAdd(&ls[3 + c], val * val);
    } else {
      pH[idx] = (col == 147) ? (ushort)0x3F80 : (ushort)0;  // 1.0f (bias col)
      pL[idx] = 0;
    }
  }
  __syncthreads();
  if (threadIdx.x < 6) atomicAdd(&st[threadIdx.x], ls[threadIdx.x]);
}

// Build transposed bf16-split projection matrices Bt[n=512][k=160]:
// rows 0..146 = rnd/colstd/(sd_c+eps); row 147 = -bias; rows 148..159 = 0.
__global__ void prep_kernel(const float* __restrict__ rnd,
                            const float* __restrict__ st,   // st1[6], st2 at +6
                            ushort* __restrict__ bH1, ushort* __restrict__ bL1,
                            ushort* __restrict__ bH2, ushort* __restrict__ bL2,
                            float Np) {
  int j = blockIdx.x * 256 + threadIdx.x;
  if (j >= 512) return;
  float sum = 0.f, q = 0.f;
  for (int f = 0; f < 147; ++f) {
    float v = rnd[f * 512 + j];
    sum += v; q = fmaf(v, v, q);
  }
  float mean = sum * (1.f / 147.f);
  float var = (q - 147.f * mean * mean) * (1.f / 146.f);
  float inv1 = 1.f / sqrtf(var);
  float b1 = 0.f, b2 = 0.f;
  size_t ro = (size_t)j * 160;
#pragma unroll
  for (int c = 0; c < 3; ++c) {
    float m1 = st[c] / Np;
    float v1 = (st[3 + c] - Np * m1 * m1) / (Np - 1.f);
    float i1 = 1.f / (sqrtf(fmaxf(v1, 0.f)) + 1e-8f);
    float m2 = st[6 + c] / Np;
    float v2 = (st[9 + c] - Np * m2 * m2) / (Np - 1.f);
    float i2 = 1.f / (sqrtf(fmaxf(v2, 0.f)) + 1e-8f);
    for (int ff = 0; ff < 49; ++ff) {
      int f = c * 49 + ff;
      float rv = rnd[f * 512 + j] * inv1;
      float w1 = rv * i1;
      float w2 = rv * i2;
      b1 = fmaf(m1, w1, b1);
      b2 = fmaf(m2, w2, b2);
      ushort h1 = f2bf(w1); bH1[ro + f] = h1; bL1[ro + f] = f2bf(w1 - bf2f(h1));
      ushort h2 = f2bf(w2); bH2[ro + f] = h2; bL2[ro + f] = f2bf(w2 - bf2f(h2));
    }
  }
  float nb1 = -b1, nb2 = -b2;
  ushort h1 = f2bf(nb1); bH1[ro + 147] = h1; bL1[ro + 147] = f2bf(nb1 - bf2f(h1));
  ushort h2 = f2bf(nb2); bH2[ro + 147] = h2; bL2[ro + 147] = f2bf(nb2 - bf2f(h2));
  for (int f = 148; f < 160; ++f) {
    bH1[ro + f] = 0; bL1[ro + f] = 0;
    bH2[ro + f] = 0; bL2[ro + f] = 0;
  }
}

// proj[n][m] (col-major, stride 16384) = p[M][160] @ Bt[512][160]^T
// bf16-split MFMA 16x16x32: block 128m x 64n, 4 waves (2m x 2n), wave 64m x 32n.
__global__ __launch_bounds__(256) void gemm_kernel(
    const ushort* __restrict__ pH, const ushort* __restrict__ pL,
    const ushort* __restrict__ bH, const ushort* __restrict__ bL,
    float* __restrict__ C) {
  __shared__ __align__(16) ushort sPH[4096], sPL[4096], sBH[2048], sBL[2048];
  int tid = threadIdx.x;
  int bm = blockIdx.x * 128, bn = blockIdx.y * 64;
  int lane = tid & 63;
  int wave = tid >> 6;
  int wm = (wave & 1) * 64, wn = (wave >> 1) * 32;
  int l15 = lane & 15, quad = lane >> 4;
  f32x4 acc[4][2] = {};
  for (int k0 = 0; k0 < 160; k0 += 32) {
    __syncthreads();
    // stage p tile: 512 16B chunks each (hi, lo); fragment order [quad][m]
#pragma unroll
    for (int c2 = 0; c2 < 2; ++c2) {
      int ch = c2 * 256 + tid;
      int qq = ch >> 7, m = ch & 127;
      size_t goff = (size_t)(bm + m) * 160 + k0 + qq * 8;
      *(int4*)(&sPH[ch * 8]) = *(const int4*)(pH + goff);
      *(int4*)(&sPL[ch * 8]) = *(const int4*)(pL + goff);
    }
    {  // stage Bt tile: 256 chunks each; fragment order [quad][n]
      int qq = tid >> 6, n = tid & 63;
      size_t goff = (size_t)(bn + n) * 160 + k0 + qq * 8;
      *(int4*)(&sBH[tid * 8]) = *(const int4*)(bH + goff);
      *(int4*)(&sBL[tid * 8]) = *(const int4*)(bL + goff);
    }
    __syncthreads();
    bf16x8 af[2][2], bfr[4][2];
#pragma unroll
    for (int nt = 0; nt < 2; ++nt) {
      int ch = quad * 64 + wn + nt * 16 + l15;
      af[nt][0] = *(const bf16x8*)(&sBH[ch * 8]);
      af[nt][1] = *(const bf16x8*)(&sBL[ch * 8]);
    }
#pragma unroll
    for (int mt = 0; mt < 4; ++mt) {
      int ch = quad * 128 + wm + mt * 16 + l15;
      bfr[mt][0] = *(const bf16x8*)(&sPH[ch * 8]);
      bfr[mt][1] = *(const bf16x8*)(&sPL[ch * 8]);
    }
#pragma unroll
    for (int mt = 0; mt < 4; ++mt)
#pragma unroll
      for (int nt = 0; nt < 2; ++nt) {
        acc[mt][nt] = __builtin_amdgcn_mfma_f32_16x16x32_bf16(
            af[nt][0], bfr[mt][0], acc[mt][nt], 0, 0, 0);
        acc[mt][nt] = __builtin_amdgcn_mfma_f32_16x16x32_bf16(
            af[nt][0], bfr[mt][1], acc[mt][nt], 0, 0, 0);
        acc[mt][nt] = __builtin_amdgcn_mfma_f32_16x16x32_bf16(
            af[nt][1], bfr[mt][0], acc[mt][nt], 0, 0, 0);
      }
  }
  int mcol = bm + wm + l15;
#pragma unroll
  for (int mt = 0; mt < 4; ++mt)
#pragma unroll
    for (int nt = 0; nt < 2; ++nt)
#pragma unroll
      for (int r = 0; r < 4; ++r) {
        int n = bn + wn + nt * 16 + quad * 4 + r;
        C[(size_t)n * 16384 + mcol + mt * 16] = acc[mt][nt][r];
      }
}

// ---- hybrid sort + diff ----
__device__ inline int corank2(const float* __restrict__ s, int pb, int L,
                              int so, int lo, int hi) {
  while (lo < hi) {
    int mid = (lo + hi) >> 1;
    if (s[pb + mid] < s[pb + L + so - 1 - mid]) lo = mid + 1; else hi = mid;
  }
  return lo;
}

__global__ __launch_bounds__(1024) void sortdiff_kernel(
    float* __restrict__ proj1, const float* __restrict__ proj2,
    float* __restrict__ sum, int m) {
  __shared__ float s[16384];
  int t = threadIdx.x;
  int col = blockIdx.x;  // 0..511
  const float INF = __builtin_huge_valf();
  float v[16];
  int bi = t << 4;
  float acc = 0.f;

  for (int phase = 0; phase < 2; ++phase) {
    float* basep = (phase ? (float*)proj2 : proj1) + (size_t)col * 16384;
    if (bi < m) {
#pragma unroll
      for (int i = 0; i < 4; ++i) {
        float4 L4 = *(const float4*)(basep + bi + i * 4);
        v[i * 4 + 0] = L4.x; v[i * 4 + 1] = L4.y;
        v[i * 4 + 2] = L4.z; v[i * 4 + 3] = L4.w;
      }
    } else {
#pragma unroll
      for (int r = 0; r < 16; ++r) v[r] = INF;
    }

    // in-thread bitonic, k=2..8
#pragma unroll
    for (int k = 2; k <= 8; k <<= 1) {
#pragma unroll
      for (int j = k >> 1; j >= 1; j >>= 1) {
#pragma unroll
        for (int r = 0; r < 16; ++r) {
          if ((r & j) == 0) {
            bool up = ((r & k) == 0);
            float a = v[r], b = v[r | j];
            float lo = fminf(a, b), hi = fmaxf(a, b);
            v[r] = up ? lo : hi;
            v[r | j] = up ? hi : lo;
          }
        }
      }
    }
    // wave-level bitonic, k=16..1024 (k=1024 forced ascending)
    for (int k = 16; k <= 1024; k <<= 1) {
      bool upk = (k == 1024) || ((bi & k) == 0);
      for (int j = k >> 1; j >= 16; j >>= 1) {
        int d = j >> 4;
        bool keepmin = (upk == ((t & d) == 0));
#pragma unroll
        for (int r = 0; r < 16; ++r) {
          float pv = __shfl_xor(v[r], d, 64);
          float lo = fminf(v[r], pv), hi = fmaxf(v[r], pv);
          v[r] = keepmin ? lo : hi;
        }
      }
#pragma unroll
      for (int j = 8; j >= 1; j >>= 1) {
#pragma unroll
        for (int r = 0; r < 16; ++r) {
          if ((r & j) == 0) {
            float a = v[r], b = v[r | j];
            float lo = fminf(a, b), hi = fmaxf(a, b);
            v[r] = upk ? lo : hi;
            v[r | j] = upk ? hi : lo;
          }
        }
      }
    }

    __syncthreads();
#pragma unroll
    for (int i = 0; i < 4; ++i)
      *(float4*)(&s[bi + i * 4]) =
          make_float4(v[i * 4], v[i * 4 + 1], v[i * 4 + 2], v[i * 4 + 3]);
    __syncthreads();

    // 4 merge-path rounds: L = 1024..8192
    for (int L = 1024; L <= 8192; L <<= 1) {
      int pb = bi & ~(2 * L - 1);
      int so = bi - pb;
      int lo0 = so - L; lo0 = lo0 < 0 ? 0 : lo0;
      int hi0 = so < L ? so : L;
      int i0 = corank2(s, pb, L, so, lo0, hi0);
      int so1 = so + 16;
      int lo1 = so1 - L; lo1 = lo1 < 0 ? 0 : lo1; lo1 = lo1 > i0 ? lo1 : i0;
      int hi1 = so1 < L ? so1 : L; hi1 = hi1 < i0 + 16 ? hi1 : i0 + 16;
      int i1 = corank2(s, pb, L, so1, lo1, hi1);
      int na = i1 - i0;
      int j1 = so1 - i1;
#pragma unroll
      for (int q = 0; q < 16; ++q) {
        int idx = (q < na) ? (pb + i0 + q)
                           : (pb + L + j1 - 1 - (q - na));
        v[q] = s[idx];
      }
#pragma unroll
      for (int j = 8; j >= 1; j >>= 1) {
#pragma unroll
        for (int q = 0; q < 16; ++q) {
          if ((q & j) == 0) {
            float a = v[q], b = v[q | j];
            v[q] = fminf(a, b);
            v[q | j] = fmaxf(a, b);
          }
        }
      }
      __syncthreads();
      if (L < 8192) {
#pragma unroll
        for (int i = 0; i < 4; ++i)
          *(float4*)(&s[bi + i * 4]) =
              make_float4(v[i * 4], v[i * 4 + 1], v[i * 4 + 2], v[i * 4 + 3]);
        __syncthreads();
      }
    }

    if (phase == 0) {
#pragma unroll
      for (int i = 0; i < 4; ++i)
        *(float4*)(basep + bi + i * 4) =
            make_float4(v[i * 4], v[i * 4 + 1], v[i * 4 + 2], v[i * 4 + 3]);
    } else if (bi < m) {
      const float* s1 = proj1 + (size_t)col * 16384;
#pragma unroll
      for (int i = 0; i < 4; ++i) {
        float4 a = *(const float4*)(s1 + bi + i * 4);
        acc += fabsf(a.x - v[i * 4 + 0]);
        acc += fabsf(a.y - v[i * 4 + 1]);
        acc += fabsf(a.z - v[i * 4 + 2]);
        acc += fabsf(a.w - v[i * 4 + 3]);
      }
    }
  }

#pragma unroll
  for (int o = 32; o > 0; o >>= 1) acc += __shfl_down(acc, o, 64);
  __syncthreads();
  if ((t & 63) == 0) s[t >> 6] = acc;
  __syncthreads();
  if (t == 0) {
    float tot = 0.f;
    for (int i = 0; i < 16; ++i) tot += s[i];
    atomicAdd(sum, tot);
  }
}

__global__ void final_kernel(const float* __restrict__ sums, float* __restrict__ out) {
  float r = sums[0] * (1.f / 8388608.f) + sums[1] * (1.f / 8388608.f) +
            sums[2] * (1.f / 8388608.f) + sums[3] * (1.f / 8388608.f) +
            sums[4] * (1.f / 6553600.f);
  out[0] = r * (1000.f / 5.f);
}

// ---------------------------------------------------------------------------

extern "C" void kernel_launch(void* const* d_in, const int* in_sizes, int n_in,
                              void* d_out, int out_size, void* d_ws, size_t ws_size,
                              hipStream_t stream) {
  const float* xin = (const float*)d_in[0];
  const float* yin = (const float*)d_in[1];
  float* out = (float*)d_out;

  char* base = (char*)d_ws;
  size_t off = 0;
  auto allocB = [&](size_t nbytes) -> void* {
    void* p = (void*)(base + off);
    off = (off + nbytes + 255) & ~(size_t)255;
    return p;
  };
  float* gX[5];
  float* gY[5];
  gX[0] = (float*)xin;
  gY[0] = (float*)yin;
  gX[1] = (float*)allocB(6291456 * 4); gX[2] = (float*)allocB(1572864 * 4);
  gX[3] = (float*)allocB(393216 * 4);  gX[4] = (float*)allocB(98304 * 4);
  gY[1] = (float*)allocB(6291456 * 4); gY[2] = (float*)allocB(1572864 * 4);
  gY[3] = (float*)allocB(393216 * 4);  gY[4] = (float*)allocB(98304 * 4);
  ushort* pH1 = (ushort*)allocB((size_t)16384 * 160 * 2);
  ushort* pL1 = (ushort*)allocB((size_t)16384 * 160 * 2);
  ushort* pH2 = (ushort*)allocB((size_t)16384 * 160 * 2);
  ushort* pL2 = (ushort*)allocB((size_t)16384 * 160 * 2);
  float* rnd = (float*)allocB(75264 * 4);
  ushort* bH1 = (ushort*)allocB(512 * 160 * 2);
  ushort* bL1 = (ushort*)allocB(512 * 160 * 2);
  ushort* bH2 = (ushort*)allocB(512 * 160 * 2);
  ushort* bL2 = (ushort*)allocB(512 * 160 * 2);
  float* proj1 = (float*)allocB((size_t)16384 * 512 * 4);
  float* proj2 = (float*)allocB((size_t)16384 * 512 * 4);
  float* misc = (float*)allocB(128 * 4);

  static const int Hs[5] = {256, 128, 64, 32, 16};

  init_kernel<<<1, 128, 0, stream>>>(misc);
  for (int t = 0; t < 2; ++t) {
    const float* in0 = t ? yin : xin;
    float** g = t ? gY : gX;
    down_kernel<<<(384 * 128 * 128 + 255) / 256, 256, 0, stream>>>(in0, g[1], 256, 256, 384 * 128 * 128);
    down_kernel<<<(384 * 64 * 64 + 255) / 256, 256, 0, stream>>>(g[1], g[2], 128, 128, 384 * 64 * 64);
    down_kernel<<<(384 * 32 * 32 + 255) / 256, 256, 0, stream>>>(g[2], g[3], 64, 64, 384 * 32 * 32);
    down_kernel<<<(384 * 16 * 16 + 255) / 256, 256, 0, stream>>>(g[3], g[4], 32, 32, 384 * 16 * 16);
  }
  for (int l = 0; l < 5; ++l) {
    int H = Hs[l];
    int Wm6 = H - 6;
    int n = Wm6 * Wm6;
    int nd = n < 128 ? n : 128;
    int M = 128 * nd;
    randgen_kernel<<<320, 256, 0, stream>>>(rnd, g_tbl.kp0[l], g_tbl.kp1[l]);
    int totalE = M * 160;
    float* st1 = misc + 8 + l * 16;
    float* st2 = st1 + 6;
    extract_kernel<<<(totalE + 255) / 256, 256, 0, stream>>>(
        gX[l], (l < 4) ? gX[l + 1] : nullptr, pH1, pL1, st1, g_tbl.rcs[l], H, nd, (l < 4) ? 1 : 0, totalE);
    extract_kernel<<<(totalE + 255) / 256, 256, 0, stream>>>(
        gY[l], (l < 4) ? gY[l + 1] : nullptr, pH2, pL2, st2, g_tbl.rcs[l], H, nd, (l < 4) ? 1 : 0, totalE);
    prep_kernel<<<2, 256, 0, stream>>>(rnd, st1, bH1, bL1, bH2, bL2, (float)M * 49.f);
    dim3 gg(M / 128, 8);
    gemm_kernel<<<gg, 256, 0, stream>>>(pH1, pL1, bH1, bL1, proj1);
    gemm_kernel<<<gg, 256, 0, stream>>>(pH2, pL2, bH2, bL2, proj2);
    sortdiff_kernel<<<512, 1024, 0, stream>>>(proj1, proj2, misc + l, M);
  }
  final_kernel<<<1, 1, 0, stream>>>(misc, out);
}